// Round 3
// baseline (1219.357 us; speedup 1.0000x reference)
//
#include <hip/hip_runtime.h>
#include <hip/hip_bf16.h>
#include <math.h>

// Problem constants
#define DDIM 1024
#define NH   16
#define LTOK 512
#define NBATCH 16

typedef unsigned short u16;
typedef unsigned short u16x8 __attribute__((ext_vector_type(8)));
typedef __bf16 bf16x8 __attribute__((ext_vector_type(8)));
typedef float f32x4 __attribute__((ext_vector_type(4)));

__device__ __forceinline__ float bf2f(u16 u) {
    unsigned v = ((unsigned)u) << 16;
    float f; __builtin_memcpy(&f, &v, 4); return f;
}
__device__ __forceinline__ u16 f2bf(float f) {
    unsigned u; __builtin_memcpy(&u, &f, 4);
    u += 0x7fffu + ((u >> 16) & 1u);   // RNE
    return (u16)(u >> 16);
}

// ---------------------------------------------------------------------------
// Generic MFMA GEMM:  C = act( scale * (A @ BT^T) + bias [+ mask] )
//   A  : M x K row-major bf16;  BT : N x K row-major bf16
//   C  : bf16 (Cb) unless Cf != nullptr, then fp32 (Cf)
// z: zb=z/zdiv, zh=z%zdiv; offsets += zb*s?1 + zh*s?2  (strides in elements)
// flags: 1 = GELU(erf), 2 = causal+padding mask (mask = fp32 dec_mask keys)
// 128x128 tile, BK=32, 4 waves 2x2, 16x16x32 bf16 MFMA.  [m93-verified shape]
// ---------------------------------------------------------------------------
__global__ __launch_bounds__(256) void gemm_bt_kernel(
    const u16* __restrict__ A, int lda, long sA1, long sA2,
    const u16* __restrict__ B, int ldb, long sB1, long sB2,
    u16* __restrict__ C, float* __restrict__ Cf, int ldc, long sC1, long sC2,
    int M, int N, int K, int zdiv,
    const float* __restrict__ bias, float scale, int flags,
    const float* __restrict__ mask)
{
    __shared__ __align__(16) u16 As[128 * 40];   // pad 32->40 (2-way banks: free)
    __shared__ __align__(16) u16 Bs[128 * 40];

    const int z  = blockIdx.y;
    const int zb = z / zdiv, zh = z - zb * zdiv;
    const u16* Ab = A + (long)zb * sA1 + (long)zh * sA2;
    const u16* Bb = B + (long)zb * sB1 + (long)zh * sB2;
    u16*   Cb  = C  ? C  + (long)zb * sC1 + (long)zh * sC2 : nullptr;
    float* Cfb = Cf ? Cf + (long)zb * sC1 + (long)zh * sC2 : nullptr;

    const int tilesN = (N + 127) >> 7;
    const int tm = blockIdx.x / tilesN, tn = blockIdx.x - tm * tilesN;
    const int m0 = tm << 7, n0 = tn << 7;

    const int tid  = threadIdx.x;
    const int lane = tid & 63;
    const int wave = tid >> 6;
    const int wm = (wave & 1) << 6, wn = (wave >> 1) << 6;
    const int quad = lane >> 4, l16 = lane & 15;

    f32x4 acc[4][4];
#pragma unroll
    for (int i = 0; i < 4; i++)
#pragma unroll
        for (int j = 0; j < 4; j++) acc[i][j] = (f32x4){0.f, 0.f, 0.f, 0.f};

    const int sr = tid >> 2;           // 0..63
    const int sc = (tid & 3) << 3;     // 0,8,16,24
    int ra0 = m0 + sr;      if (ra0 > M - 1) ra0 = M - 1;
    int ra1 = m0 + sr + 64; if (ra1 > M - 1) ra1 = M - 1;
    int rb0 = n0 + sr;      if (rb0 > N - 1) rb0 = N - 1;
    int rb1 = n0 + sr + 64; if (rb1 > N - 1) rb1 = N - 1;
    const u16* pa0 = Ab + (long)ra0 * lda + sc;
    const u16* pa1 = Ab + (long)ra1 * lda + sc;
    const u16* pb0 = Bb + (long)rb0 * ldb + sc;
    const u16* pb1 = Bb + (long)rb1 * ldb + sc;

    for (int k0 = 0; k0 < K; k0 += 32) {
        u16x8 va0 = *(const u16x8*)(pa0 + k0);
        u16x8 va1 = *(const u16x8*)(pa1 + k0);
        u16x8 vb0 = *(const u16x8*)(pb0 + k0);
        u16x8 vb1 = *(const u16x8*)(pb1 + k0);
        __syncthreads();
        *(u16x8*)(As + sr * 40 + sc)        = va0;
        *(u16x8*)(As + (sr + 64) * 40 + sc) = va1;
        *(u16x8*)(Bs + sr * 40 + sc)        = vb0;
        *(u16x8*)(Bs + (sr + 64) * 40 + sc) = vb1;
        __syncthreads();

        bf16x8 af[4], bfr[4];
#pragma unroll
        for (int t = 0; t < 4; t++)
            af[t] = *(const bf16x8*)(As + (wm + t * 16 + l16) * 40 + quad * 8);
#pragma unroll
        for (int t = 0; t < 4; t++)
            bfr[t] = *(const bf16x8*)(Bs + (wn + t * 16 + l16) * 40 + quad * 8);
#pragma unroll
        for (int i = 0; i < 4; i++)
#pragma unroll
            for (int j = 0; j < 4; j++)
                acc[i][j] = __builtin_amdgcn_mfma_f32_16x16x32_bf16(
                    af[i], bfr[j], acc[i][j], 0, 0, 0);
    }

    // epilogue: C/D layout = col lane&15 (n), row quad*4+r (m)  [m89/m91]
#pragma unroll
    for (int j = 0; j < 4; j++) {
        int col  = n0 + wn + j * 16 + l16;
        int colc = col < N ? col : N - 1;
        float bv   = bias ? bias[colc] : 0.f;
        float mval = (flags & 2) ? mask[zb * LTOK + colc] : 0.f;
#pragma unroll
        for (int i = 0; i < 4; i++) {
#pragma unroll
            for (int r = 0; r < 4; r++) {
                int row = m0 + wm + i * 16 + quad * 4 + r;
                float v = acc[i][j][r] * scale + bv;
                if (flags & 2) {   // + (1 - dec_mask[k]*causal)*(-1e4)
                    float mk = (col <= row) ? mval : 0.f;
                    v += (1.f - mk) * (-10000.f);
                }
                if (flags & 1)
                    v = 0.5f * v * (1.f + erff(v * 0.70710678118654752f));
                v = fminf(fmaxf(v, -3.0e38f), 3.0e38f);   // sanitize (NaN -> -3e38)
                if (row < M && col < N) {
                    if (Cfb) Cfb[(long)row * ldc + col] = v;
                    else     Cb [(long)row * ldc + col] = f2bf(v);
                }
            }
        }
    }
}

// Row softmax over 512 cols, one wave per row, in-place bf16.
__global__ __launch_bounds__(256) void softmax_kernel(u16* __restrict__ S)
{
    long row = (long)blockIdx.x * 4 + (threadIdx.x >> 6);
    int lane = threadIdx.x & 63;
    u16* p = S + row * LTOK + lane * 8;
    u16x8 raw = *(const u16x8*)p;
    float f[8]; float m = -3.0e38f;
#pragma unroll
    for (int j = 0; j < 8; j++) {
        f[j] = fminf(fmaxf(bf2f(raw[j]), -30000.f), 30000.f);
        m = fmaxf(m, f[j]);
    }
#pragma unroll
    for (int ofs = 32; ofs >= 1; ofs >>= 1) m = fmaxf(m, __shfl_xor(m, ofs));
    float s = 0.f;
#pragma unroll
    for (int j = 0; j < 8; j++) { f[j] = __expf(f[j] - m); s += f[j]; }
#pragma unroll
    for (int ofs = 32; ofs >= 1; ofs >>= 1) s += __shfl_xor(s, ofs);
    float inv = 1.f / s;
    u16x8 o;
#pragma unroll
    for (int j = 0; j < 8; j++) o[j] = f2bf(f[j] * inv);
    *(u16x8*)p = o;
}

// out = LayerNorm(a + b) * g + beta.  a: bf16.  b: bf16 unless b32 (fp32).
// Output: bf16 (o) unless of != nullptr (fp32).  Row length 1024.
__global__ __launch_bounds__(256) void add_ln_kernel(
    const u16* __restrict__ a, const u16* __restrict__ b,
    const float* __restrict__ b32,
    const float* __restrict__ g, const float* __restrict__ bt,
    u16* __restrict__ o, float* __restrict__ of)
{
    long row = blockIdx.x;
    int tid = threadIdx.x;
    __shared__ float red[4];
    const u16* ar = a + row * DDIM;
    float xv[4]; float s = 0.f;
#pragma unroll
    for (int i = 0; i < 4; i++) {
        int c = tid + 256 * i;
        float sum = bf2f(ar[c]) + (b32 ? b32[row * DDIM + c] : bf2f(b[row * DDIM + c]));
        xv[i] = fminf(fmaxf(sum, -1.0e18f), 1.0e18f);
        s += xv[i];
    }
#pragma unroll
    for (int ofs = 32; ofs >= 1; ofs >>= 1) s += __shfl_xor(s, ofs);
    int wave = tid >> 6, lane = tid & 63;
    if (lane == 0) red[wave] = s;
    __syncthreads();
    float mu = (red[0] + red[1] + red[2] + red[3]) * (1.f / 1024.f);
    __syncthreads();
    float v = 0.f;
#pragma unroll
    for (int i = 0; i < 4; i++) { float d = xv[i] - mu; v += d * d; }
#pragma unroll
    for (int ofs = 32; ofs >= 1; ofs >>= 1) v += __shfl_xor(v, ofs);
    if (lane == 0) red[wave] = v;
    __syncthreads();
    float var = (red[0] + red[1] + red[2] + red[3]) * (1.f / 1024.f);
    float inv = rsqrtf(var + 1e-6f);
#pragma unroll
    for (int i = 0; i < 4; i++) {
        int c = tid + 256 * i;
        float r = (xv[i] - mu) * inv * g[c] + bt[c];
        if (of) of[row * DDIM + c] = r;
        else    o [row * DDIM + c] = f2bf(r);
    }
}

// fp32 -> bf16 conversion, 8 elements/thread.
__global__ __launch_bounds__(256) void cvt_kernel(
    const float* __restrict__ src, u16* __restrict__ dst)
{
    long i = ((long)blockIdx.x * 256 + threadIdx.x) * 8;
    u16x8 o;
#pragma unroll
    for (int j = 0; j < 8; j++) o[j] = f2bf(src[i + j]);
    *(u16x8*)(dst + i) = o;
}

// Transpose+cvt the 8 fp32 weight matrices (1024x1024): WT[n][k] = bf16(W[k][n])
__global__ __launch_bounds__(256) void wt_kernel(
    const float* w0, const float* w1, const float* w2, const float* w3,
    const float* w4, const float* w5, const float* w6, const float* w7,
    u16* __restrict__ wt)
{
    const float* srcs[8] = {w0, w1, w2, w3, w4, w5, w6, w7};
    const float* w = srcs[blockIdx.z];
    u16* o = wt + (long)blockIdx.z * DDIM * DDIM;
    __shared__ u16 t[32][33];
    int tx = threadIdx.x & 31, ty = threadIdx.x >> 5;
    int c0 = blockIdx.x << 5, r0 = blockIdx.y << 5;
#pragma unroll
    for (int i = 0; i < 4; i++)
        t[ty + 8 * i][tx] = f2bf(w[(long)(r0 + ty + 8 * i) * DDIM + c0 + tx]);
    __syncthreads();
#pragma unroll
    for (int i = 0; i < 4; i++)
        o[(long)(c0 + ty + 8 * i) * DDIM + r0 + tx] = t[tx][ty + 8 * i];
}

// vt[(b*NH+h)*64 + dd][k] = v[b*LTOK + k][h*64 + dd]   (per-head V transpose)
__global__ __launch_bounds__(256) void vtrans_kernel(
    const u16* __restrict__ v, u16* __restrict__ vt)
{
    int bh = blockIdx.y; int b = bh >> 4, h = bh & 15;
    int k0 = blockIdx.x << 5;
    __shared__ __align__(16) u16 t[32 * 72];
    int kk = threadIdx.x >> 3, c = (threadIdx.x & 7) << 3;
    u16x8 val = *(const u16x8*)(v + ((long)b * LTOK + k0 + kk) * DDIM + h * 64 + c);
    *(u16x8*)(t + kk * 72 + c) = val;
    __syncthreads();
    int dd = threadIdx.x >> 2, k2 = (threadIdx.x & 3) << 3;
    u16x8 o;
#pragma unroll
    for (int j = 0; j < 8; j++) o[j] = t[(k2 + j) * 72 + dd];
    *(u16x8*)(vt + ((long)bh * 64 + dd) * LTOK + k0 + k2) = o;
}

extern "C" void kernel_launch(void* const* d_in, const int* in_sizes, int n_in,
                              void* d_out, int out_size, void* d_ws, size_t ws_size,
                              hipStream_t stream)
{
    const float* x     = (const float*)d_in[0];
    const float* dmsk  = (const float*)d_in[1];
    const float* enc   = (const float*)d_in[2];
    const float* sa_wq = (const float*)d_in[3];  const float* sa_bq = (const float*)d_in[4];
    const float* sa_wk = (const float*)d_in[5];  const float* sa_bk = (const float*)d_in[6];
    const float* sa_wv = (const float*)d_in[7];  const float* sa_bv = (const float*)d_in[8];
    const float* n1_g  = (const float*)d_in[9];  const float* n1_b  = (const float*)d_in[10];
    const float* ca_wq = (const float*)d_in[11]; const float* ca_bq = (const float*)d_in[12];
    const float* ca_wk = (const float*)d_in[13]; const float* ca_bk = (const float*)d_in[14];
    const float* ca_wv = (const float*)d_in[15]; const float* ca_bv = (const float*)d_in[16];
    const float* n2_g  = (const float*)d_in[17]; const float* n2_b  = (const float*)d_in[18];
    const float* int_w = (const float*)d_in[19]; const float* int_b = (const float*)d_in[20];
    const float* out_w = (const float*)d_in[21]; const float* out_b = (const float*)d_in[22];
    const float* out_g = (const float*)d_in[23]; const float* out_bt= (const float*)d_in[24];

    float* outp = (float*)d_out;
    float* visp = outp + (long)NBATCH * LTOK * DDIM;   // attention_vis (fp32)

    // --- workspace: chunk over batches; per chunk 7 act buffers + scores ---
    const size_t WTB  = (size_t)8 * DDIM * DDIM * 2;            // 16 MiB
    const size_t BUF1 = (size_t)LTOK * DDIM * 2;                // 1 MiB / batch
    const size_t SCB1 = (size_t)NH * LTOK * LTOK * 2;           // 8 MiB / batch
    int cb = 16;
    while (cb > 1 && WTB + (size_t)cb * (7 * BUF1 + SCB1) + 8192 > ws_size)
        cb >>= 1;

    char* ws = (char*)d_ws;
    size_t off = 0;
    auto alloc = [&](size_t bytes) -> u16* {
        u16* p = (u16*)(ws + off);
        off += (bytes + 255) & ~(size_t)255;
        return p;
    };
    u16* Bq  = alloc((size_t)cb * BUF1);
    u16* Bk  = alloc((size_t)cb * BUF1);
    u16* Bv  = alloc((size_t)cb * BUF1);
    u16* Bt  = alloc((size_t)cb * BUF1);
    u16* Bt2 = alloc((size_t)cb * BUF1);
    u16* Xb  = alloc((size_t)cb * BUF1);
    u16* Eb  = alloc((size_t)cb * BUF1);
    u16* WT  = alloc(WTB);
    u16* SC  = alloc((size_t)cb * SCB1);

    size_t zbytes = off <= ws_size ? off : ws_size;
    hipMemsetAsync(d_ws, 0, zbytes, stream);

    u16* Wsaq = WT + 0L * DDIM * DDIM; u16* Wsak = WT + 1L * DDIM * DDIM;
    u16* Wsav = WT + 2L * DDIM * DDIM; u16* Wcaq = WT + 3L * DDIM * DDIM;
    u16* Wcak = WT + 4L * DDIM * DDIM; u16* Wcav = WT + 5L * DDIM * DDIM;
    u16* Wint = WT + 6L * DDIM * DDIM; u16* Wout = WT + 7L * DDIM * DDIM;

    auto gemm = [&](const u16* A, int lda, long sA1, long sA2,
                    const u16* B, int ldb, long sB1, long sB2,
                    u16* C, float* Cf, int ldc, long sC1, long sC2,
                    int M, int N, int K, int Z, int zdiv,
                    const float* bias, float scale, int flags, const float* mask) {
        int tM = (M + 127) / 128, tN = (N + 127) / 128;
        gemm_bt_kernel<<<dim3(tM * tN, Z), dim3(256), 0, stream>>>(
            A, lda, sA1, sA2, B, ldb, sB1, sB2, C, Cf, ldc, sC1, sC2,
            M, N, K, zdiv, bias, scale, flags, mask);
    };

    const long SLD = (long)LTOK * DDIM;       // per-batch row-block stride
    const long SSC = (long)LTOK * LTOK;       // scores per (b,h)
    const long SVT = (long)64 * LTOK;         // vt per head

    // 0) weight transposes + bf16 cvt (once per call)
    wt_kernel<<<dim3(32, 32, 8), dim3(256), 0, stream>>>(
        sa_wq, sa_wk, sa_wv, ca_wq, ca_wk, ca_wv, int_w, out_w, WT);

    for (int b0 = 0; b0 < NBATCH; b0 += cb) {
        const float* xc = x   + (long)b0 * SLD;
        const float* ec = enc + (long)b0 * SLD;
        const int M = cb * LTOK;
        const int Z = cb * NH;
        const int cvtg = (int)(((long)M * DDIM) / (256 * 8));

        // a) fp32 -> bf16 activation copies
        cvt_kernel<<<dim3(cvtg), dim3(256), 0, stream>>>(xc, Xb);
        cvt_kernel<<<dim3(cvtg), dim3(256), 0, stream>>>(ec, Eb);

        // 1) self-attn q,k,v projections
        gemm(Xb, DDIM, 0, 0, Wsaq, DDIM, 0, 0, Bq, nullptr, DDIM, 0, 0, M, DDIM, DDIM, 1, 1, sa_bq, 1.f, 0, nullptr);
        gemm(Xb, DDIM, 0, 0, Wsak, DDIM, 0, 0, Bk, nullptr, DDIM, 0, 0, M, DDIM, DDIM, 1, 1, sa_bk, 1.f, 0, nullptr);
        gemm(Xb, DDIM, 0, 0, Wsav, DDIM, 0, 0, Bv, nullptr, DDIM, 0, 0, M, DDIM, DDIM, 1, 1, sa_bv, 1.f, 0, nullptr);
        vtrans_kernel<<<dim3(16, Z), dim3(256), 0, stream>>>(Bv, Bt);

        // 2) self-attention: scores -> softmax -> ctx (ctx overwrites Bv)
        gemm(Bq, DDIM, SLD, 64, Bk, DDIM, SLD, 64,
             SC, nullptr, LTOK, (long)NH * SSC, SSC,
             LTOK, LTOK, 64, Z, NH, nullptr, 0.125f, 2, dmsk + (long)b0 * LTOK);
        softmax_kernel<<<dim3(Z * LTOK / 4), dim3(256), 0, stream>>>(SC);
        gemm(SC, LTOK, (long)NH * SSC, SSC, Bt, LTOK, (long)NH * SVT, SVT,
             Bv, nullptr, DDIM, SLD, 64, LTOK, 64, LTOK, Z, NH, nullptr, 1.f, 0, nullptr);

        // 3) h = LN(ctx + x_fp32) -> Bq
        add_ln_kernel<<<dim3(M), dim3(256), 0, stream>>>(
            Bv, nullptr, xc, n1_g, n1_b, Bq, nullptr);

        // 4) cross projections: cq->Bk, ck->Bv, cv->Bt
        gemm(Bq, DDIM, 0, 0, Wcaq, DDIM, 0, 0, Bk, nullptr, DDIM, 0, 0, M, DDIM, DDIM, 1, 1, ca_bq, 1.f, 0, nullptr);
        gemm(Eb, DDIM, 0, 0, Wcak, DDIM, 0, 0, Bv, nullptr, DDIM, 0, 0, M, DDIM, DDIM, 1, 1, ca_bk, 1.f, 0, nullptr);
        gemm(Eb, DDIM, 0, 0, Wcav, DDIM, 0, 0, Bt, nullptr, DDIM, 0, 0, M, DDIM, DDIM, 1, 1, ca_bv, 1.f, 0, nullptr);

        // 5) attention_vis = (cq @ ck^T) / 128  -> fp32 d_out
        gemm(Bk, DDIM, SLD, 0, Bv, DDIM, SLD, 0,
             nullptr, visp + (long)b0 * SSC, LTOK, SSC, 0,
             LTOK, LTOK, DDIM, cb, 1, nullptr, 1.f / 128.f, 0, nullptr);

        // 6) cross-attention: vt(cv)->Bt2; scores; ctx -> Bt
        vtrans_kernel<<<dim3(16, Z), dim3(256), 0, stream>>>(Bt, Bt2);
        gemm(Bk, DDIM, SLD, 64, Bv, DDIM, SLD, 64,
             SC, nullptr, LTOK, (long)NH * SSC, SSC,
             LTOK, LTOK, 64, Z, NH, nullptr, 0.125f, 0, nullptr);
        softmax_kernel<<<dim3(Z * LTOK / 4), dim3(256), 0, stream>>>(SC);
        gemm(SC, LTOK, (long)NH * SSC, SSC, Bt2, LTOK, (long)NH * SVT, SVT,
             Bt, nullptr, DDIM, SLD, 64, LTOK, 64, LTOK, Z, NH, nullptr, 1.f, 0, nullptr);

        // 7) h2 = LN(h + cactx) -> Bv
        add_ln_kernel<<<dim3(M), dim3(256), 0, stream>>>(
            Bq, Bt, nullptr, n2_g, n2_b, Bv, nullptr);

        // 8) inter = gelu(h2 @ int_w + int_b) -> Bk
        gemm(Bv, DDIM, 0, 0, Wint, DDIM, 0, 0, Bk, nullptr, DDIM, 0, 0, M, DDIM, DDIM, 1, 1, int_b, 1.f, 1, nullptr);
        // 9) G = inter @ out_w + out_b -> Bt
        gemm(Bk, DDIM, 0, 0, Wout, DDIM, 0, 0, Bt, nullptr, DDIM, 0, 0, M, DDIM, DDIM, 1, 1, out_b, 1.f, 0, nullptr);
        // 10) out = LN(G + inter) -> fp32 d_out
        add_ln_kernel<<<dim3(M), dim3(256), 0, stream>>>(
            Bt, Bk, nullptr, out_g, out_bt, nullptr, outp + (long)b0 * SLD);
    }
}

// Round 4
// 1197.586 us; speedup vs baseline: 1.0182x; 1.0182x over previous
//
#include <hip/hip_runtime.h>
#include <hip/hip_bf16.h>
#include <math.h>

// Problem constants
#define DDIM 1024
#define NH   16
#define LTOK 512
#define NBATCH 16

typedef unsigned short u16;
typedef unsigned short u16x8 __attribute__((ext_vector_type(8)));
typedef __bf16 bf16x8 __attribute__((ext_vector_type(8)));
typedef float f32x4 __attribute__((ext_vector_type(4)));

typedef __attribute__((address_space(1))) void as1_void;
typedef __attribute__((address_space(3))) void as3_void;

__device__ __forceinline__ void llds16(const u16* g, u16* l) {
    // async 16B global->LDS DMA; LDS dest = wave-uniform base + lane*16B
    __builtin_amdgcn_global_load_lds((as1_void*)g, (as3_void*)l, 16, 0, 0);
}

__device__ __forceinline__ float bf2f(u16 u) {
    unsigned v = ((unsigned)u) << 16;
    float f; __builtin_memcpy(&f, &v, 4); return f;
}
__device__ __forceinline__ u16 f2bf(float f) {
    unsigned u; __builtin_memcpy(&u, &f, 4);
    u += 0x7fffu + ((u >> 16) & 1u);   // RNE
    return (u16)(u >> 16);
}

// ---------------------------------------------------------------------------
// Generic MFMA GEMM:  C = act( scale * (A @ BT^T) + bias [+ mask] )
//   A  : M x K row-major bf16;  BT : N x K row-major bf16
//   C  : bf16 (Cb) unless Cf != nullptr, then fp32 (Cf)
// z: zb=z/zdiv, zh=z%zdiv; offsets += zb*s?1 + zh*s?2  (strides in elements)
// flags: 1 = GELU(erf), 2 = causal+padding mask (mask = fp32 dec_mask keys)
// 128x128 tile, BK=32, 4 waves 2x2, 16x16x32 bf16 MFMA.
// Staging: global_load_lds width=16 (m97 ladder step), unpadded stride-32 LDS
// (DMA writes lane*16B contiguous -- padding would break the layout, m104/108).
// ---------------------------------------------------------------------------
__global__ __launch_bounds__(256) void gemm_bt_kernel(
    const u16* __restrict__ A, int lda, long sA1, long sA2,
    const u16* __restrict__ B, int ldb, long sB1, long sB2,
    u16* __restrict__ C, float* __restrict__ Cf, int ldc, long sC1, long sC2,
    int M, int N, int K, int zdiv,
    const float* __restrict__ bias, float scale, int flags,
    const float* __restrict__ mask)
{
    __shared__ __align__(16) u16 As[128 * 32];
    __shared__ __align__(16) u16 Bs[128 * 32];

    const int z  = blockIdx.y;
    const int zb = z / zdiv, zh = z - zb * zdiv;
    const u16* Ab = A + (long)zb * sA1 + (long)zh * sA2;
    const u16* Bb = B + (long)zb * sB1 + (long)zh * sB2;
    u16*   Cb  = C  ? C  + (long)zb * sC1 + (long)zh * sC2 : nullptr;
    float* Cfb = Cf ? Cf + (long)zb * sC1 + (long)zh * sC2 : nullptr;

    const int tilesN = (N + 127) >> 7;
    const int tm = blockIdx.x / tilesN, tn = blockIdx.x - tm * tilesN;
    const int m0 = tm << 7, n0 = tn << 7;

    const int tid  = threadIdx.x;
    const int lane = tid & 63;
    const int wave = tid >> 6;
    const int wm = (wave & 1) << 6, wn = (wave >> 1) << 6;
    const int quad = lane >> 4, l16 = lane & 15;

    f32x4 acc[4][4];
#pragma unroll
    for (int i = 0; i < 4; i++)
#pragma unroll
        for (int j = 0; j < 4; j++) acc[i][j] = (f32x4){0.f, 0.f, 0.f, 0.f};

    // staging map: wave covers 32 rows (2 DMA issues x 16 rows); within an
    // issue, lane -> row (wave*32 + q*16 + lane/4), col (lane%4)*8
    const int lrA = (wave << 5) + (lane >> 2);
    const int lc  = (lane & 3) << 3;
    int ra0 = m0 + lrA;      if (ra0 > M - 1) ra0 = M - 1;
    int ra1 = m0 + lrA + 16; if (ra1 > M - 1) ra1 = M - 1;
    int rb0 = n0 + lrA;      if (rb0 > N - 1) rb0 = N - 1;
    int rb1 = n0 + lrA + 16; if (rb1 > N - 1) rb1 = N - 1;
    const u16* gA0 = Ab + (long)ra0 * lda + lc;
    const u16* gA1 = Ab + (long)ra1 * lda + lc;
    const u16* gB0 = Bb + (long)rb0 * ldb + lc;
    const u16* gB1 = Bb + (long)rb1 * ldb + lc;
    u16* lA0 = As + ((wave << 5) +  0) * 32;   // wave-uniform LDS bases
    u16* lA1 = As + ((wave << 5) + 16) * 32;
    u16* lB0 = Bs + ((wave << 5) +  0) * 32;
    u16* lB1 = Bs + ((wave << 5) + 16) * 32;

    for (int k0 = 0; k0 < K; k0 += 32) {
        __syncthreads();                 // prior frag reads done before overwrite
        llds16(gA0 + k0, lA0);
        llds16(gA1 + k0, lA1);
        llds16(gB0 + k0, lB0);
        llds16(gB1 + k0, lB1);
        __syncthreads();                 // drains vmcnt: DMA visible to all

        bf16x8 af[4], bfr[4];
#pragma unroll
        for (int t = 0; t < 4; t++)
            af[t] = *(const bf16x8*)(As + (wm + t * 16 + l16) * 32 + quad * 8);
#pragma unroll
        for (int t = 0; t < 4; t++)
            bfr[t] = *(const bf16x8*)(Bs + (wn + t * 16 + l16) * 32 + quad * 8);
#pragma unroll
        for (int i = 0; i < 4; i++)
#pragma unroll
            for (int j = 0; j < 4; j++)
                acc[i][j] = __builtin_amdgcn_mfma_f32_16x16x32_bf16(
                    af[i], bfr[j], acc[i][j], 0, 0, 0);
    }

    // epilogue: C/D layout = col lane&15 (n), row quad*4+r (m)  [m89/m91]
#pragma unroll
    for (int j = 0; j < 4; j++) {
        int col  = n0 + wn + j * 16 + l16;
        int colc = col < N ? col : N - 1;
        float bv   = bias ? bias[colc] : 0.f;
        float mval = (flags & 2) ? mask[zb * LTOK + colc] : 0.f;
#pragma unroll
        for (int i = 0; i < 4; i++) {
#pragma unroll
            for (int r = 0; r < 4; r++) {
                int row = m0 + wm + i * 16 + quad * 4 + r;
                float v = acc[i][j][r] * scale + bv;
                if (flags & 2) {   // + (1 - dec_mask[k]*causal)*(-1e4)
                    float mk = (col <= row) ? mval : 0.f;
                    v += (1.f - mk) * (-10000.f);
                }
                if (flags & 1)
                    v = 0.5f * v * (1.f + erff(v * 0.70710678118654752f));
                v = fminf(fmaxf(v, -3.0e38f), 3.0e38f);
                if (row < M && col < N) {
                    if (Cfb) Cfb[(long)row * ldc + col] = v;
                    else     Cb [(long)row * ldc + col] = f2bf(v);
                }
            }
        }
    }
}

// Row softmax over 512 cols, one wave per row, in-place bf16.
__global__ __launch_bounds__(256) void softmax_kernel(u16* __restrict__ S)
{
    long row = (long)blockIdx.x * 4 + (threadIdx.x >> 6);
    int lane = threadIdx.x & 63;
    u16* p = S + row * LTOK + lane * 8;
    u16x8 raw = *(const u16x8*)p;
    float f[8]; float m = -3.0e38f;
#pragma unroll
    for (int j = 0; j < 8; j++) {
        f[j] = fminf(fmaxf(bf2f(raw[j]), -30000.f), 30000.f);
        m = fmaxf(m, f[j]);
    }
#pragma unroll
    for (int ofs = 32; ofs >= 1; ofs >>= 1) m = fmaxf(m, __shfl_xor(m, ofs));
    float s = 0.f;
#pragma unroll
    for (int j = 0; j < 8; j++) { f[j] = __expf(f[j] - m); s += f[j]; }
#pragma unroll
    for (int ofs = 32; ofs >= 1; ofs >>= 1) s += __shfl_xor(s, ofs);
    float inv = 1.f / s;
    u16x8 o;
#pragma unroll
    for (int j = 0; j < 8; j++) o[j] = f2bf(f[j] * inv);
    *(u16x8*)p = o;
}

// out = LayerNorm(a + b) * g + beta.  a: bf16.  b: bf16 unless b32 (fp32).
// Output: bf16 (o) unless of != nullptr (fp32).  Row length 1024.
__global__ __launch_bounds__(256) void add_ln_kernel(
    const u16* __restrict__ a, const u16* __restrict__ b,
    const float* __restrict__ b32,
    const float* __restrict__ g, const float* __restrict__ bt,
    u16* __restrict__ o, float* __restrict__ of)
{
    long row = blockIdx.x;
    int tid = threadIdx.x;
    __shared__ float red[4];
    const u16* ar = a + row * DDIM;
    float xv[4]; float s = 0.f;
#pragma unroll
    for (int i = 0; i < 4; i++) {
        int c = tid + 256 * i;
        float sum = bf2f(ar[c]) + (b32 ? b32[row * DDIM + c] : bf2f(b[row * DDIM + c]));
        xv[i] = fminf(fmaxf(sum, -1.0e18f), 1.0e18f);
        s += xv[i];
    }
#pragma unroll
    for (int ofs = 32; ofs >= 1; ofs >>= 1) s += __shfl_xor(s, ofs);
    int wave = tid >> 6, lane = tid & 63;
    if (lane == 0) red[wave] = s;
    __syncthreads();
    float mu = (red[0] + red[1] + red[2] + red[3]) * (1.f / 1024.f);
    __syncthreads();
    float v = 0.f;
#pragma unroll
    for (int i = 0; i < 4; i++) { float d = xv[i] - mu; v += d * d; }
#pragma unroll
    for (int ofs = 32; ofs >= 1; ofs >>= 1) v += __shfl_xor(v, ofs);
    if (lane == 0) red[wave] = v;
    __syncthreads();
    float var = (red[0] + red[1] + red[2] + red[3]) * (1.f / 1024.f);
    float inv = rsqrtf(var + 1e-6f);
#pragma unroll
    for (int i = 0; i < 4; i++) {
        int c = tid + 256 * i;
        float r = (xv[i] - mu) * inv * g[c] + bt[c];
        if (of) of[row * DDIM + c] = r;
        else    o [row * DDIM + c] = f2bf(r);
    }
}

// fp32 -> bf16 conversion, 8 elements/thread.
__global__ __launch_bounds__(256) void cvt_kernel(
    const float* __restrict__ src, u16* __restrict__ dst)
{
    long i = ((long)blockIdx.x * 256 + threadIdx.x) * 8;
    u16x8 o;
#pragma unroll
    for (int j = 0; j < 8; j++) o[j] = f2bf(src[i + j]);
    *(u16x8*)(dst + i) = o;
}

// Transpose+cvt the 8 fp32 weight matrices (1024x1024): WT[n][k] = bf16(W[k][n])
__global__ __launch_bounds__(256) void wt_kernel(
    const float* w0, const float* w1, const float* w2, const float* w3,
    const float* w4, const float* w5, const float* w6, const float* w7,
    u16* __restrict__ wt)
{
    const float* srcs[8] = {w0, w1, w2, w3, w4, w5, w6, w7};
    const float* w = srcs[blockIdx.z];
    u16* o = wt + (long)blockIdx.z * DDIM * DDIM;
    __shared__ u16 t[32][33];
    int tx = threadIdx.x & 31, ty = threadIdx.x >> 5;
    int c0 = blockIdx.x << 5, r0 = blockIdx.y << 5;
#pragma unroll
    for (int i = 0; i < 4; i++)
        t[ty + 8 * i][tx] = f2bf(w[(long)(r0 + ty + 8 * i) * DDIM + c0 + tx]);
    __syncthreads();
#pragma unroll
    for (int i = 0; i < 4; i++)
        o[(long)(c0 + ty + 8 * i) * DDIM + r0 + tx] = t[tx][ty + 8 * i];
}

// vt[(b*NH+h)*64 + dd][k] = v[b*LTOK + k][h*64 + dd]   (per-head V transpose)
__global__ __launch_bounds__(256) void vtrans_kernel(
    const u16* __restrict__ v, u16* __restrict__ vt)
{
    int bh = blockIdx.y; int b = bh >> 4, h = bh & 15;
    int k0 = blockIdx.x << 5;
    __shared__ __align__(16) u16 t[32 * 72];
    int kk = threadIdx.x >> 3, c = (threadIdx.x & 7) << 3;
    u16x8 val = *(const u16x8*)(v + ((long)b * LTOK + k0 + kk) * DDIM + h * 64 + c);
    *(u16x8*)(t + kk * 72 + c) = val;
    __syncthreads();
    int dd = threadIdx.x >> 2, k2 = (threadIdx.x & 3) << 3;
    u16x8 o;
#pragma unroll
    for (int j = 0; j < 8; j++) o[j] = t[(k2 + j) * 72 + dd];
    *(u16x8*)(vt + ((long)bh * 64 + dd) * LTOK + k0 + k2) = o;
}

extern "C" void kernel_launch(void* const* d_in, const int* in_sizes, int n_in,
                              void* d_out, int out_size, void* d_ws, size_t ws_size,
                              hipStream_t stream)
{
    const float* x     = (const float*)d_in[0];
    const float* dmsk  = (const float*)d_in[1];
    const float* enc   = (const float*)d_in[2];
    const float* sa_wq = (const float*)d_in[3];  const float* sa_bq = (const float*)d_in[4];
    const float* sa_wk = (const float*)d_in[5];  const float* sa_bk = (const float*)d_in[6];
    const float* sa_wv = (const float*)d_in[7];  const float* sa_bv = (const float*)d_in[8];
    const float* n1_g  = (const float*)d_in[9];  const float* n1_b  = (const float*)d_in[10];
    const float* ca_wq = (const float*)d_in[11]; const float* ca_bq = (const float*)d_in[12];
    const float* ca_wk = (const float*)d_in[13]; const float* ca_bk = (const float*)d_in[14];
    const float* ca_wv = (const float*)d_in[15]; const float* ca_bv = (const float*)d_in[16];
    const float* n2_g  = (const float*)d_in[17]; const float* n2_b  = (const float*)d_in[18];
    const float* int_w = (const float*)d_in[19]; const float* int_b = (const float*)d_in[20];
    const float* out_w = (const float*)d_in[21]; const float* out_b = (const float*)d_in[22];
    const float* out_g = (const float*)d_in[23]; const float* out_bt= (const float*)d_in[24];

    float* outp = (float*)d_out;
    float* visp = outp + (long)NBATCH * LTOK * DDIM;   // attention_vis (fp32)

    // --- workspace: chunk over batches; per chunk 7 act buffers + scores ---
    const size_t WTB  = (size_t)8 * DDIM * DDIM * 2;            // 16 MiB
    const size_t BUF1 = (size_t)LTOK * DDIM * 2;                // 1 MiB / batch
    const size_t SCB1 = (size_t)NH * LTOK * LTOK * 2;           // 8 MiB / batch
    int cb = 16;
    while (cb > 1 && WTB + (size_t)cb * (7 * BUF1 + SCB1) + 8192 > ws_size)
        cb >>= 1;

    char* ws = (char*)d_ws;
    size_t off = 0;
    auto alloc = [&](size_t bytes) -> u16* {
        u16* p = (u16*)(ws + off);
        off += (bytes + 255) & ~(size_t)255;
        return p;
    };
    u16* Bq  = alloc((size_t)cb * BUF1);
    u16* Bk  = alloc((size_t)cb * BUF1);
    u16* Bv  = alloc((size_t)cb * BUF1);
    u16* Bt  = alloc((size_t)cb * BUF1);
    u16* Bt2 = alloc((size_t)cb * BUF1);
    u16* Xb  = alloc((size_t)cb * BUF1);
    u16* Eb  = alloc((size_t)cb * BUF1);
    u16* WT  = alloc(WTB);
    u16* SC  = alloc((size_t)cb * SCB1);
    // NOTE: no memset needed -- every ws region is fully written before read
    // (Xb/Eb by cvt, WT by wt_kernel, Bq..Bt2 by full-M gemms, SC by QK gemm).

    u16* Wsaq = WT + 0L * DDIM * DDIM; u16* Wsak = WT + 1L * DDIM * DDIM;
    u16* Wsav = WT + 2L * DDIM * DDIM; u16* Wcaq = WT + 3L * DDIM * DDIM;
    u16* Wcak = WT + 4L * DDIM * DDIM; u16* Wcav = WT + 5L * DDIM * DDIM;
    u16* Wint = WT + 6L * DDIM * DDIM; u16* Wout = WT + 7L * DDIM * DDIM;

    auto gemm = [&](const u16* A, int lda, long sA1, long sA2,
                    const u16* B, int ldb, long sB1, long sB2,
                    u16* C, float* Cf, int ldc, long sC1, long sC2,
                    int M, int N, int K, int Z, int zdiv,
                    const float* bias, float scale, int flags, const float* mask) {
        int tM = (M + 127) / 128, tN = (N + 127) / 128;
        gemm_bt_kernel<<<dim3(tM * tN, Z), dim3(256), 0, stream>>>(
            A, lda, sA1, sA2, B, ldb, sB1, sB2, C, Cf, ldc, sC1, sC2,
            M, N, K, zdiv, bias, scale, flags, mask);
    };

    const long SLD = (long)LTOK * DDIM;       // per-batch row-block stride
    const long SSC = (long)LTOK * LTOK;       // scores per (b,h)
    const long SVT = (long)64 * LTOK;         // vt per head

    // 0) weight transposes + bf16 cvt (once per call)
    wt_kernel<<<dim3(32, 32, 8), dim3(256), 0, stream>>>(
        sa_wq, sa_wk, sa_wv, ca_wq, ca_wk, ca_wv, int_w, out_w, WT);

    for (int b0 = 0; b0 < NBATCH; b0 += cb) {
        const float* xc = x   + (long)b0 * SLD;
        const float* ec = enc + (long)b0 * SLD;
        const int M = cb * LTOK;
        const int Z = cb * NH;
        const int cvtg = (int)(((long)M * DDIM) / (256 * 8));

        // a) fp32 -> bf16 activation copies
        cvt_kernel<<<dim3(cvtg), dim3(256), 0, stream>>>(xc, Xb);
        cvt_kernel<<<dim3(cvtg), dim3(256), 0, stream>>>(ec, Eb);

        // 1) self-attn q,k,v projections
        gemm(Xb, DDIM, 0, 0, Wsaq, DDIM, 0, 0, Bq, nullptr, DDIM, 0, 0, M, DDIM, DDIM, 1, 1, sa_bq, 1.f, 0, nullptr);
        gemm(Xb, DDIM, 0, 0, Wsak, DDIM, 0, 0, Bk, nullptr, DDIM, 0, 0, M, DDIM, DDIM, 1, 1, sa_bk, 1.f, 0, nullptr);
        gemm(Xb, DDIM, 0, 0, Wsav, DDIM, 0, 0, Bv, nullptr, DDIM, 0, 0, M, DDIM, DDIM, 1, 1, sa_bv, 1.f, 0, nullptr);
        vtrans_kernel<<<dim3(16, Z), dim3(256), 0, stream>>>(Bv, Bt);

        // 2) self-attention: scores -> softmax -> ctx (ctx overwrites Bv)
        gemm(Bq, DDIM, SLD, 64, Bk, DDIM, SLD, 64,
             SC, nullptr, LTOK, (long)NH * SSC, SSC,
             LTOK, LTOK, 64, Z, NH, nullptr, 0.125f, 2, dmsk + (long)b0 * LTOK);
        softmax_kernel<<<dim3(Z * LTOK / 4), dim3(256), 0, stream>>>(SC);
        gemm(SC, LTOK, (long)NH * SSC, SSC, Bt, LTOK, (long)NH * SVT, SVT,
             Bv, nullptr, DDIM, SLD, 64, LTOK, 64, LTOK, Z, NH, nullptr, 1.f, 0, nullptr);

        // 3) h = LN(ctx + x_fp32) -> Bq
        add_ln_kernel<<<dim3(M), dim3(256), 0, stream>>>(
            Bv, nullptr, xc, n1_g, n1_b, Bq, nullptr);

        // 4) cross projections: cq->Bk, ck->Bv, cv->Bt
        gemm(Bq, DDIM, 0, 0, Wcaq, DDIM, 0, 0, Bk, nullptr, DDIM, 0, 0, M, DDIM, DDIM, 1, 1, ca_bq, 1.f, 0, nullptr);
        gemm(Eb, DDIM, 0, 0, Wcak, DDIM, 0, 0, Bv, nullptr, DDIM, 0, 0, M, DDIM, DDIM, 1, 1, ca_bk, 1.f, 0, nullptr);
        gemm(Eb, DDIM, 0, 0, Wcav, DDIM, 0, 0, Bt, nullptr, DDIM, 0, 0, M, DDIM, DDIM, 1, 1, ca_bv, 1.f, 0, nullptr);

        // 5) attention_vis = (cq @ ck^T) / 128  -> fp32 d_out
        gemm(Bk, DDIM, SLD, 0, Bv, DDIM, SLD, 0,
             nullptr, visp + (long)b0 * SSC, LTOK, SSC, 0,
             LTOK, LTOK, DDIM, cb, 1, nullptr, 1.f / 128.f, 0, nullptr);

        // 6) cross-attention: vt(cv)->Bt2; scores; ctx -> Bt
        vtrans_kernel<<<dim3(16, Z), dim3(256), 0, stream>>>(Bt, Bt2);
        gemm(Bk, DDIM, SLD, 64, Bv, DDIM, SLD, 64,
             SC, nullptr, LTOK, (long)NH * SSC, SSC,
             LTOK, LTOK, 64, Z, NH, nullptr, 0.125f, 0, nullptr);
        softmax_kernel<<<dim3(Z * LTOK / 4), dim3(256), 0, stream>>>(SC);
        gemm(SC, LTOK, (long)NH * SSC, SSC, Bt2, LTOK, (long)NH * SVT, SVT,
             Bt, nullptr, DDIM, SLD, 64, LTOK, 64, LTOK, Z, NH, nullptr, 1.f, 0, nullptr);

        // 7) h2 = LN(h + cactx) -> Bv
        add_ln_kernel<<<dim3(M), dim3(256), 0, stream>>>(
            Bq, Bt, nullptr, n2_g, n2_b, Bv, nullptr);

        // 8) inter = gelu(h2 @ int_w + int_b) -> Bk
        gemm(Bv, DDIM, 0, 0, Wint, DDIM, 0, 0, Bk, nullptr, DDIM, 0, 0, M, DDIM, DDIM, 1, 1, int_b, 1.f, 1, nullptr);
        // 9) G = inter @ out_w + out_b -> Bt
        gemm(Bk, DDIM, 0, 0, Wout, DDIM, 0, 0, Bt, nullptr, DDIM, 0, 0, M, DDIM, DDIM, 1, 1, out_b, 1.f, 0, nullptr);
        // 10) out = LN(G + inter) -> fp32 d_out
        add_ln_kernel<<<dim3(M), dim3(256), 0, stream>>>(
            Bt, Bk, nullptr, out_g, out_bt, nullptr, outp + (long)b0 * SLD);
    }
}

// Round 5
// 854.947 us; speedup vs baseline: 1.4262x; 1.4008x over previous
//
#include <hip/hip_runtime.h>
#include <hip/hip_bf16.h>
#include <math.h>

// Problem constants
#define DDIM 1024
#define NH   16
#define LTOK 512
#define NBATCH 16

typedef unsigned short u16;
typedef unsigned short u16x8 __attribute__((ext_vector_type(8)));
typedef __bf16 bf16x8 __attribute__((ext_vector_type(8)));
typedef float f32x4 __attribute__((ext_vector_type(4)));

typedef __attribute__((address_space(1))) void as1_void;
typedef __attribute__((address_space(3))) void as3_void;

__device__ __forceinline__ void llds16(const u16* g, u16* l) {
    // async 16B global->LDS DMA; LDS dest = wave-uniform base + lane*16B
    __builtin_amdgcn_global_load_lds((as1_void*)g, (as3_void*)l, 16, 0, 0);
}

__device__ __forceinline__ float bf2f(u16 u) {
    unsigned v = ((unsigned)u) << 16;
    float f; __builtin_memcpy(&f, &v, 4); return f;
}
__device__ __forceinline__ u16 f2bf(float f) {
    unsigned u; __builtin_memcpy(&u, &f, 4);
    u += 0x7fffu + ((u >> 16) & 1u);   // RNE
    return (u16)(u >> 16);
}

// ---------------------------------------------------------------------------
// Generic MFMA GEMM (projections / vis):  C = act(scale*(A@BT^T)+bias)
// 128x128 tile, BK=32, global_load_lds staging (m97 shape). K>=512 users only.
// ---------------------------------------------------------------------------
__global__ __launch_bounds__(256) void gemm_bt_kernel(
    const u16* __restrict__ A, int lda, long sA1, long sA2,
    const u16* __restrict__ B, int ldb, long sB1, long sB2,
    u16* __restrict__ C, float* __restrict__ Cf, int ldc, long sC1, long sC2,
    int M, int N, int K, int zdiv,
    const float* __restrict__ bias, float scale, int flags)
{
    __shared__ __align__(16) u16 As[128 * 32];
    __shared__ __align__(16) u16 Bs[128 * 32];

    const int z  = blockIdx.y;
    const int zb = z / zdiv, zh = z - zb * zdiv;
    const u16* Ab = A + (long)zb * sA1 + (long)zh * sA2;
    const u16* Bb = B + (long)zb * sB1 + (long)zh * sB2;
    u16*   Cb  = C  ? C  + (long)zb * sC1 + (long)zh * sC2 : nullptr;
    float* Cfb = Cf ? Cf + (long)zb * sC1 + (long)zh * sC2 : nullptr;

    const int tilesN = (N + 127) >> 7;
    const int tm = blockIdx.x / tilesN, tn = blockIdx.x - tm * tilesN;
    const int m0 = tm << 7, n0 = tn << 7;

    const int tid  = threadIdx.x;
    const int lane = tid & 63;
    const int wave = tid >> 6;
    const int wm = (wave & 1) << 6, wn = (wave >> 1) << 6;
    const int quad = lane >> 4, l16 = lane & 15;

    f32x4 acc[4][4];
#pragma unroll
    for (int i = 0; i < 4; i++)
#pragma unroll
        for (int j = 0; j < 4; j++) acc[i][j] = (f32x4){0.f, 0.f, 0.f, 0.f};

    const int lrA = (wave << 5) + (lane >> 2);
    const int lc  = (lane & 3) << 3;
    int ra0 = m0 + lrA;      if (ra0 > M - 1) ra0 = M - 1;
    int ra1 = m0 + lrA + 16; if (ra1 > M - 1) ra1 = M - 1;
    int rb0 = n0 + lrA;      if (rb0 > N - 1) rb0 = N - 1;
    int rb1 = n0 + lrA + 16; if (rb1 > N - 1) rb1 = N - 1;
    const u16* gA0 = Ab + (long)ra0 * lda + lc;
    const u16* gA1 = Ab + (long)ra1 * lda + lc;
    const u16* gB0 = Bb + (long)rb0 * ldb + lc;
    const u16* gB1 = Bb + (long)rb1 * ldb + lc;
    u16* lA0 = As + ((wave << 5) +  0) * 32;
    u16* lA1 = As + ((wave << 5) + 16) * 32;
    u16* lB0 = Bs + ((wave << 5) +  0) * 32;
    u16* lB1 = Bs + ((wave << 5) + 16) * 32;

    for (int k0 = 0; k0 < K; k0 += 32) {
        __syncthreads();
        llds16(gA0 + k0, lA0);
        llds16(gA1 + k0, lA1);
        llds16(gB0 + k0, lB0);
        llds16(gB1 + k0, lB1);
        __syncthreads();

        bf16x8 af[4], bfr[4];
#pragma unroll
        for (int t = 0; t < 4; t++)
            af[t] = *(const bf16x8*)(As + (wm + t * 16 + l16) * 32 + quad * 8);
#pragma unroll
        for (int t = 0; t < 4; t++)
            bfr[t] = *(const bf16x8*)(Bs + (wn + t * 16 + l16) * 32 + quad * 8);
#pragma unroll
        for (int i = 0; i < 4; i++)
#pragma unroll
            for (int j = 0; j < 4; j++)
                acc[i][j] = __builtin_amdgcn_mfma_f32_16x16x32_bf16(
                    af[i], bfr[j], acc[i][j], 0, 0, 0);
    }

#pragma unroll
    for (int j = 0; j < 4; j++) {
        int col  = n0 + wn + j * 16 + l16;
        int colc = col < N ? col : N - 1;
        float bv = bias ? bias[colc] : 0.f;
#pragma unroll
        for (int i = 0; i < 4; i++) {
#pragma unroll
            for (int r = 0; r < 4; r++) {
                int row = m0 + wm + i * 16 + quad * 4 + r;
                float v = acc[i][j][r] * scale + bv;
                if (flags & 1)
                    v = 0.5f * v * (1.f + erff(v * 0.70710678118654752f));
                if (row < M && col < N) {
                    if (Cfb) Cfb[(long)row * ldc + col] = v;
                    else     Cb [(long)row * ldc + col] = f2bf(v);
                }
            }
        }
    }
}

// ---------------------------------------------------------------------------
// Flash attention: O = softmax(scale*Q K^T + mask) V, head dim 64, L = 512.
//   Q,K,O: (b, 512, 1024) bf16, head h at cols h*64..h*64+63
//   VT   : (bh, 64, 512) bf16 (per-head V^T, from vtrans)
// grid (8, cb*16): qt = blockIdx.x (64 q-rows), bh = blockIdx.y.
// 4 waves/block, each owns 16 q-rows — fully independent (no barriers):
// Q frags in registers; K/VT frags read straight from global (L2-hot);
// P does the C-layout -> A-layout transform via per-wave-private LDS (m120).
// Online softmax state (m,l) per lane rows quad*4+r == C-layout rows.
// ---------------------------------------------------------------------------
__global__ __launch_bounds__(256) void flash_kernel(
    const u16* __restrict__ Q, const u16* __restrict__ K,
    const u16* __restrict__ VT, u16* __restrict__ O,
    const float* __restrict__ mask, int causal)
{
    __shared__ __align__(16) u16 Ps[64 * 136];   // 4 waves x 16 rows, pad 128->136
    const int tid  = threadIdx.x;
    const int wave = tid >> 6, lane = tid & 63;
    const int quad = lane >> 4, l16 = lane & 15;
    const int qt = blockIdx.x, bh = blockIdx.y, b = bh >> 4, h = bh & 15;
    const int qbase = qt * 64 + wave * 16;

    // Q A-frags (m=l16, k=quad*8+j) held for the whole kernel
    const u16* qp = Q + ((long)b * LTOK + qbase + l16) * DDIM + h * 64 + quad * 8;
    bf16x8 aq0 = *(const bf16x8*)(qp);
    bf16x8 aq1 = *(const bf16x8*)(qp + 32);

    f32x4 oacc[4];
#pragma unroll
    for (int jd = 0; jd < 4; jd++) oacc[jd] = (f32x4){0.f, 0.f, 0.f, 0.f};
    f32x4 m_st = (f32x4){-3.0e38f, -3.0e38f, -3.0e38f, -3.0e38f};
    f32x4 l_st = (f32x4){0.f, 0.f, 0.f, 0.f};

    u16* Pw = Ps + (wave * 16) * 136;   // private rows: no inter-wave sync

    const int nkt = causal ? ((qbase + 15) >> 7) + 1 : (LTOK >> 7);
    for (int kt = 0; kt < nkt; kt++) {
        const int k0 = kt << 7;

        // S-tile = Q K^T : C-layout (row q = quad*4+r, col key = j*16+l16)
        f32x4 s[8];
#pragma unroll
        for (int j = 0; j < 8; j++) s[j] = (f32x4){0.f, 0.f, 0.f, 0.f};
#pragma unroll
        for (int j = 0; j < 8; j++) {
            const u16* kp = K + ((long)b * LTOK + k0 + j * 16 + l16) * DDIM
                              + h * 64 + quad * 8;
            bf16x8 bk0 = *(const bf16x8*)(kp);
            bf16x8 bk1 = *(const bf16x8*)(kp + 32);
            s[j] = __builtin_amdgcn_mfma_f32_16x16x32_bf16(aq0, bk0, s[j], 0, 0, 0);
            s[j] = __builtin_amdgcn_mfma_f32_16x16x32_bf16(aq1, bk1, s[j], 0, 0, 0);
        }

        // scale + mask, per-row tile max
        f32x4 tmax = (f32x4){-3.0e38f, -3.0e38f, -3.0e38f, -3.0e38f};
#pragma unroll
        for (int j = 0; j < 8; j++) {
            const int col = k0 + j * 16 + l16;
            float mval = causal ? mask[b * LTOK + col] : 0.f;
#pragma unroll
            for (int r = 0; r < 4; r++) {
                float v = s[j][r] * 0.125f;
                if (causal) {
                    const int row = qbase + quad * 4 + r;
                    float mk = (col <= row) ? mval : 0.f;
                    v += (1.f - mk) * (-10000.f);
                }
                s[j][r] = v;
                tmax[r] = fmaxf(tmax[r], v);
            }
        }
#pragma unroll
        for (int ofs = 1; ofs <= 8; ofs <<= 1) {
#pragma unroll
            for (int r = 0; r < 4; r++)
                tmax[r] = fmaxf(tmax[r], __shfl_xor(tmax[r], ofs));
        }

        f32x4 mnew, alpha, rsum;
#pragma unroll
        for (int r = 0; r < 4; r++) {
            mnew[r]  = fmaxf(m_st[r], tmax[r]);
            alpha[r] = __expf(m_st[r] - mnew[r]);
            rsum[r]  = 0.f;
        }
        // P = exp(s - mnew), write to private LDS rows (natural q x key layout)
#pragma unroll
        for (int j = 0; j < 8; j++) {
#pragma unroll
            for (int r = 0; r < 4; r++) {
                float p = __expf(s[j][r] - mnew[r]);
                rsum[r] += p;
                Pw[(quad * 4 + r) * 136 + j * 16 + l16] = f2bf(p);
            }
        }
#pragma unroll
        for (int ofs = 1; ofs <= 8; ofs <<= 1) {
#pragma unroll
            for (int r = 0; r < 4; r++)
                rsum[r] += __shfl_xor(rsum[r], ofs);
        }
#pragma unroll
        for (int r = 0; r < 4; r++) {
            l_st[r] = l_st[r] * alpha[r] + rsum[r];
            m_st[r] = mnew[r];
        }
#pragma unroll
        for (int jd = 0; jd < 4; jd++)
#pragma unroll
            for (int r = 0; r < 4; r++) oacc[jd][r] *= alpha[r];

        // O += P @ V : A = P (A-layout from LDS), B = VT rows (global, L2-hot)
#pragma unroll
        for (int kk = 0; kk < 4; kk++) {
            bf16x8 ap = *(const bf16x8*)(Ps + (wave * 16 + l16) * 136
                                            + kk * 32 + quad * 8);
#pragma unroll
            for (int jd = 0; jd < 4; jd++) {
                bf16x8 bv = *(const bf16x8*)(VT + ((long)bh * 64 + jd * 16 + l16) * LTOK
                                                + k0 + kk * 32 + quad * 8);
                oacc[jd] = __builtin_amdgcn_mfma_f32_16x16x32_bf16(ap, bv, oacc[jd], 0, 0, 0);
            }
        }
    }

    // O write: element (q = quad*4+r, d = jd*16+l16)
#pragma unroll
    for (int jd = 0; jd < 4; jd++) {
#pragma unroll
        for (int r = 0; r < 4; r++) {
            long row = (long)b * LTOK + qbase + quad * 4 + r;
            O[row * DDIM + h * 64 + jd * 16 + l16] = f2bf(oacc[jd][r] / l_st[r]);
        }
    }
}

// out = LayerNorm(a + b) * g + beta.  a: bf16.  b: bf16 unless b32 (fp32).
// Output: bf16 (o) unless of != nullptr (fp32).  Row length 1024.
__global__ __launch_bounds__(256) void add_ln_kernel(
    const u16* __restrict__ a, const u16* __restrict__ b,
    const float* __restrict__ b32,
    const float* __restrict__ g, const float* __restrict__ bt,
    u16* __restrict__ o, float* __restrict__ of)
{
    long row = blockIdx.x;
    int tid = threadIdx.x;
    __shared__ float red[4];
    const u16* ar = a + row * DDIM;
    float xv[4]; float s = 0.f;
#pragma unroll
    for (int i = 0; i < 4; i++) {
        int c = tid + 256 * i;
        float sum = bf2f(ar[c]) + (b32 ? b32[row * DDIM + c] : bf2f(b[row * DDIM + c]));
        xv[i] = fminf(fmaxf(sum, -1.0e18f), 1.0e18f);
        s += xv[i];
    }
#pragma unroll
    for (int ofs = 32; ofs >= 1; ofs >>= 1) s += __shfl_xor(s, ofs);
    int wave = tid >> 6, lane = tid & 63;
    if (lane == 0) red[wave] = s;
    __syncthreads();
    float mu = (red[0] + red[1] + red[2] + red[3]) * (1.f / 1024.f);
    __syncthreads();
    float v = 0.f;
#pragma unroll
    for (int i = 0; i < 4; i++) { float d = xv[i] - mu; v += d * d; }
#pragma unroll
    for (int ofs = 32; ofs >= 1; ofs >>= 1) v += __shfl_xor(v, ofs);
    if (lane == 0) red[wave] = v;
    __syncthreads();
    float var = (red[0] + red[1] + red[2] + red[3]) * (1.f / 1024.f);
    float inv = rsqrtf(var + 1e-6f);
#pragma unroll
    for (int i = 0; i < 4; i++) {
        int c = tid + 256 * i;
        float r = (xv[i] - mu) * inv * g[c] + bt[c];
        if (of) of[row * DDIM + c] = r;
        else    o [row * DDIM + c] = f2bf(r);
    }
}

// fp32 -> bf16 conversion, 8 elements/thread.
__global__ __launch_bounds__(256) void cvt_kernel(
    const float* __restrict__ src, u16* __restrict__ dst)
{
    long i = ((long)blockIdx.x * 256 + threadIdx.x) * 8;
    u16x8 o;
#pragma unroll
    for (int j = 0; j < 8; j++) o[j] = f2bf(src[i + j]);
    *(u16x8*)(dst + i) = o;
}

// Transpose+cvt the 8 fp32 weight matrices (1024x1024): WT[n][k] = bf16(W[k][n])
__global__ __launch_bounds__(256) void wt_kernel(
    const float* w0, const float* w1, const float* w2, const float* w3,
    const float* w4, const float* w5, const float* w6, const float* w7,
    u16* __restrict__ wt)
{
    const float* srcs[8] = {w0, w1, w2, w3, w4, w5, w6, w7};
    const float* w = srcs[blockIdx.z];
    u16* o = wt + (long)blockIdx.z * DDIM * DDIM;
    __shared__ u16 t[32][33];
    int tx = threadIdx.x & 31, ty = threadIdx.x >> 5;
    int c0 = blockIdx.x << 5, r0 = blockIdx.y << 5;
#pragma unroll
    for (int i = 0; i < 4; i++)
        t[ty + 8 * i][tx] = f2bf(w[(long)(r0 + ty + 8 * i) * DDIM + c0 + tx]);
    __syncthreads();
#pragma unroll
    for (int i = 0; i < 4; i++)
        o[(long)(c0 + ty + 8 * i) * DDIM + r0 + tx] = t[tx][ty + 8 * i];
}

// vt[(b*NH+h)*64 + dd][k] = v[b*LTOK + k][h*64 + dd]   (per-head V transpose)
__global__ __launch_bounds__(256) void vtrans_kernel(
    const u16* __restrict__ v, u16* __restrict__ vt)
{
    int bh = blockIdx.y; int b = bh >> 4, h = bh & 15;
    int k0 = blockIdx.x << 5;
    __shared__ __align__(16) u16 t[32 * 72];
    int kk = threadIdx.x >> 3, c = (threadIdx.x & 7) << 3;
    u16x8 val = *(const u16x8*)(v + ((long)b * LTOK + k0 + kk) * DDIM + h * 64 + c);
    *(u16x8*)(t + kk * 72 + c) = val;
    __syncthreads();
    int dd = threadIdx.x >> 2, k2 = (threadIdx.x & 3) << 3;
    u16x8 o;
#pragma unroll
    for (int j = 0; j < 8; j++) o[j] = t[(k2 + j) * 72 + dd];
    *(u16x8*)(vt + ((long)bh * 64 + dd) * LTOK + k0 + k2) = o;
}

extern "C" void kernel_launch(void* const* d_in, const int* in_sizes, int n_in,
                              void* d_out, int out_size, void* d_ws, size_t ws_size,
                              hipStream_t stream)
{
    const float* x     = (const float*)d_in[0];
    const float* dmsk  = (const float*)d_in[1];
    const float* enc   = (const float*)d_in[2];
    const float* sa_wq = (const float*)d_in[3];  const float* sa_bq = (const float*)d_in[4];
    const float* sa_wk = (const float*)d_in[5];  const float* sa_bk = (const float*)d_in[6];
    const float* sa_wv = (const float*)d_in[7];  const float* sa_bv = (const float*)d_in[8];
    const float* n1_g  = (const float*)d_in[9];  const float* n1_b  = (const float*)d_in[10];
    const float* ca_wq = (const float*)d_in[11]; const float* ca_bq = (const float*)d_in[12];
    const float* ca_wk = (const float*)d_in[13]; const float* ca_bk = (const float*)d_in[14];
    const float* ca_wv = (const float*)d_in[15]; const float* ca_bv = (const float*)d_in[16];
    const float* n2_g  = (const float*)d_in[17]; const float* n2_b  = (const float*)d_in[18];
    const float* int_w = (const float*)d_in[19]; const float* int_b = (const float*)d_in[20];
    const float* out_w = (const float*)d_in[21]; const float* out_b = (const float*)d_in[22];
    const float* out_g = (const float*)d_in[23]; const float* out_bt= (const float*)d_in[24];

    float* outp = (float*)d_out;
    float* visp = outp + (long)NBATCH * LTOK * DDIM;   // attention_vis (fp32)

    // --- workspace: chunk over batches; 7 act buffers / batch + WT ---
    const size_t WTB  = (size_t)8 * DDIM * DDIM * 2;            // 16 MiB
    const size_t BUF1 = (size_t)LTOK * DDIM * 2;                // 1 MiB / batch
    int cb = 16;
    while (cb > 1 && WTB + (size_t)cb * 7 * BUF1 + 8192 > ws_size)
        cb >>= 1;

    char* ws = (char*)d_ws;
    size_t off = 0;
    auto alloc = [&](size_t bytes) -> u16* {
        u16* p = (u16*)(ws + off);
        off += (bytes + 255) & ~(size_t)255;
        return p;
    };
    u16* Bq  = alloc((size_t)cb * BUF1);
    u16* Bk  = alloc((size_t)cb * BUF1);
    u16* Bv  = alloc((size_t)cb * BUF1);
    u16* Bt  = alloc((size_t)cb * BUF1);
    u16* Bt2 = alloc((size_t)cb * BUF1);
    u16* Xb  = alloc((size_t)cb * BUF1);
    u16* Eb  = alloc((size_t)cb * BUF1);
    u16* WT  = alloc(WTB);
    // no memset needed: every region fully written before read.

    u16* Wsaq = WT + 0L * DDIM * DDIM; u16* Wsak = WT + 1L * DDIM * DDIM;
    u16* Wsav = WT + 2L * DDIM * DDIM; u16* Wcaq = WT + 3L * DDIM * DDIM;
    u16* Wcak = WT + 4L * DDIM * DDIM; u16* Wcav = WT + 5L * DDIM * DDIM;
    u16* Wint = WT + 6L * DDIM * DDIM; u16* Wout = WT + 7L * DDIM * DDIM;

    auto gemm = [&](const u16* A, int lda, long sA1, long sA2,
                    const u16* B, int ldb, long sB1, long sB2,
                    u16* C, float* Cf, int ldc, long sC1, long sC2,
                    int M, int N, int K, int Z, int zdiv,
                    const float* bias, float scale, int flags) {
        int tM = (M + 127) / 128, tN = (N + 127) / 128;
        gemm_bt_kernel<<<dim3(tM * tN, Z), dim3(256), 0, stream>>>(
            A, lda, sA1, sA2, B, ldb, sB1, sB2, C, Cf, ldc, sC1, sC2,
            M, N, K, zdiv, bias, scale, flags);
    };

    const long SLD = (long)LTOK * DDIM;       // per-batch row-block stride
    const long SSC = (long)LTOK * LTOK;       // vis elems per batch

    // 0) weight transposes + bf16 cvt (once per call)
    wt_kernel<<<dim3(32, 32, 8), dim3(256), 0, stream>>>(
        sa_wq, sa_wk, sa_wv, ca_wq, ca_wk, ca_wv, int_w, out_w, WT);

    for (int b0 = 0; b0 < NBATCH; b0 += cb) {
        const float* xc = x   + (long)b0 * SLD;
        const float* ec = enc + (long)b0 * SLD;
        const int M = cb * LTOK;
        const int Z = cb * NH;
        const int cvtg = (int)(((long)M * DDIM) / (256 * 8));

        // a) fp32 -> bf16 activation copies
        cvt_kernel<<<dim3(cvtg), dim3(256), 0, stream>>>(xc, Xb);
        cvt_kernel<<<dim3(cvtg), dim3(256), 0, stream>>>(ec, Eb);

        // 1) self-attn q,k,v projections
        gemm(Xb, DDIM, 0, 0, Wsaq, DDIM, 0, 0, Bq, nullptr, DDIM, 0, 0, M, DDIM, DDIM, 1, 1, sa_bq, 1.f, 0);
        gemm(Xb, DDIM, 0, 0, Wsak, DDIM, 0, 0, Bk, nullptr, DDIM, 0, 0, M, DDIM, DDIM, 1, 1, sa_bk, 1.f, 0);
        gemm(Xb, DDIM, 0, 0, Wsav, DDIM, 0, 0, Bv, nullptr, DDIM, 0, 0, M, DDIM, DDIM, 1, 1, sa_bv, 1.f, 0);
        vtrans_kernel<<<dim3(16, Z), dim3(256), 0, stream>>>(Bv, Bt);

        // 2) self-attention (flash, causal+padding), ctx -> Bv
        flash_kernel<<<dim3(8, Z), dim3(256), 0, stream>>>(
            Bq, Bk, Bt, Bv, dmsk + (long)b0 * LTOK, 1);

        // 3) h = LN(ctx + x_fp32) -> Bq
        add_ln_kernel<<<dim3(M), dim3(256), 0, stream>>>(
            Bv, nullptr, xc, n1_g, n1_b, Bq, nullptr);

        // 4) cross projections: cq->Bk, ck->Bv, cv->Bt
        gemm(Bq, DDIM, 0, 0, Wcaq, DDIM, 0, 0, Bk, nullptr, DDIM, 0, 0, M, DDIM, DDIM, 1, 1, ca_bq, 1.f, 0);
        gemm(Eb, DDIM, 0, 0, Wcak, DDIM, 0, 0, Bv, nullptr, DDIM, 0, 0, M, DDIM, DDIM, 1, 1, ca_bk, 1.f, 0);
        gemm(Eb, DDIM, 0, 0, Wcav, DDIM, 0, 0, Bt, nullptr, DDIM, 0, 0, M, DDIM, DDIM, 1, 1, ca_bv, 1.f, 0);

        // 5) attention_vis = (cq @ ck^T) / 128  -> fp32 d_out
        gemm(Bk, DDIM, SLD, 0, Bv, DDIM, SLD, 0,
             nullptr, visp + (long)b0 * SSC, LTOK, SSC, 0,
             LTOK, LTOK, DDIM, cb, 1, nullptr, 1.f / 128.f, 0);

        // 6) cross-attention (flash, no mask): vt(cv)->Bt2; ctx -> Bt
        vtrans_kernel<<<dim3(16, Z), dim3(256), 0, stream>>>(Bt, Bt2);
        flash_kernel<<<dim3(8, Z), dim3(256), 0, stream>>>(
            Bk, Bv, Bt2, Bt, nullptr, 0);

        // 7) h2 = LN(h + cactx) -> Bv
        add_ln_kernel<<<dim3(M), dim3(256), 0, stream>>>(
            Bq, Bt, nullptr, n2_g, n2_b, Bv, nullptr);

        // 8) inter = gelu(h2 @ int_w + int_b) -> Bk
        gemm(Bv, DDIM, 0, 0, Wint, DDIM, 0, 0, Bk, nullptr, DDIM, 0, 0, M, DDIM, DDIM, 1, 1, int_b, 1.f, 1);
        // 9) G = inter @ out_w + out_b -> Bt
        gemm(Bk, DDIM, 0, 0, Wout, DDIM, 0, 0, Bt, nullptr, DDIM, 0, 0, M, DDIM, DDIM, 1, 1, out_b, 1.f, 0);
        // 10) out = LN(G + inter) -> fp32 d_out
        add_ln_kernel<<<dim3(M), dim3(256), 0, stream>>>(
            Bt, Bk, nullptr, out_g, out_bt, nullptr, outp + (long)b0 * SLD);
    }
}

// Round 6
// 670.647 us; speedup vs baseline: 1.8182x; 1.2748x over previous
//
#include <hip/hip_runtime.h>
#include <hip/hip_bf16.h>
#include <math.h>

// Problem constants
#define DDIM 1024
#define NH   16
#define LTOK 512
#define NBATCH 16

typedef unsigned short u16;
typedef unsigned short u16x8 __attribute__((ext_vector_type(8)));
typedef __bf16 bf16x8 __attribute__((ext_vector_type(8)));
typedef float f32x4 __attribute__((ext_vector_type(4)));

typedef __attribute__((address_space(1))) void as1_void;
typedef __attribute__((address_space(3))) void as3_void;

__device__ __forceinline__ void llds16(const u16* g, u16* l) {
    // async 16B global->LDS DMA; LDS dest = wave-uniform base + lane*16B
    __builtin_amdgcn_global_load_lds((as1_void*)g, (as3_void*)l, 16, 0, 0);
}

__device__ __forceinline__ float bf2f(u16 u) {
    unsigned v = ((unsigned)u) << 16;
    float f; __builtin_memcpy(&f, &v, 4); return f;
}
__device__ __forceinline__ u16 f2bf(float f) {
    unsigned u; __builtin_memcpy(&u, &f, 4);
    u += 0x7fffu + ((u >> 16) & 1u);   // RNE
    return (u16)(u >> 16);
}

// ---------------------------------------------------------------------------
// Generic MFMA GEMM (projections / vis):  C = act(scale*(A@BT^T)+bias)
// 128x128 tile, BK=32, global_load_lds staging (m97 shape). K>=512 users only.
// ---------------------------------------------------------------------------
__global__ __launch_bounds__(256) void gemm_bt_kernel(
    const u16* __restrict__ A, int lda, long sA1, long sA2,
    const u16* __restrict__ B, int ldb, long sB1, long sB2,
    u16* __restrict__ C, float* __restrict__ Cf, int ldc, long sC1, long sC2,
    int M, int N, int K, int zdiv,
    const float* __restrict__ bias, float scale, int flags)
{
    __shared__ __align__(16) u16 As[128 * 32];
    __shared__ __align__(16) u16 Bs[128 * 32];

    const int z  = blockIdx.y;
    const int zb = z / zdiv, zh = z - zb * zdiv;
    const u16* Ab = A + (long)zb * sA1 + (long)zh * sA2;
    const u16* Bb = B + (long)zb * sB1 + (long)zh * sB2;
    u16*   Cb  = C  ? C  + (long)zb * sC1 + (long)zh * sC2 : nullptr;
    float* Cfb = Cf ? Cf + (long)zb * sC1 + (long)zh * sC2 : nullptr;

    const int tilesN = (N + 127) >> 7;
    const int tm = blockIdx.x / tilesN, tn = blockIdx.x - tm * tilesN;
    const int m0 = tm << 7, n0 = tn << 7;

    const int tid  = threadIdx.x;
    const int lane = tid & 63;
    const int wave = tid >> 6;
    const int wm = (wave & 1) << 6, wn = (wave >> 1) << 6;
    const int quad = lane >> 4, l16 = lane & 15;

    f32x4 acc[4][4];
#pragma unroll
    for (int i = 0; i < 4; i++)
#pragma unroll
        for (int j = 0; j < 4; j++) acc[i][j] = (f32x4){0.f, 0.f, 0.f, 0.f};

    const int lrA = (wave << 5) + (lane >> 2);
    const int lc  = (lane & 3) << 3;
    int ra0 = m0 + lrA;      if (ra0 > M - 1) ra0 = M - 1;
    int ra1 = m0 + lrA + 16; if (ra1 > M - 1) ra1 = M - 1;
    int rb0 = n0 + lrA;      if (rb0 > N - 1) rb0 = N - 1;
    int rb1 = n0 + lrA + 16; if (rb1 > N - 1) rb1 = N - 1;
    const u16* gA0 = Ab + (long)ra0 * lda + lc;
    const u16* gA1 = Ab + (long)ra1 * lda + lc;
    const u16* gB0 = Bb + (long)rb0 * ldb + lc;
    const u16* gB1 = Bb + (long)rb1 * ldb + lc;
    u16* lA0 = As + ((wave << 5) +  0) * 32;
    u16* lA1 = As + ((wave << 5) + 16) * 32;
    u16* lB0 = Bs + ((wave << 5) +  0) * 32;
    u16* lB1 = Bs + ((wave << 5) + 16) * 32;

    for (int k0 = 0; k0 < K; k0 += 32) {
        __syncthreads();
        llds16(gA0 + k0, lA0);
        llds16(gA1 + k0, lA1);
        llds16(gB0 + k0, lB0);
        llds16(gB1 + k0, lB1);
        __syncthreads();

        bf16x8 af[4], bfr[4];
#pragma unroll
        for (int t = 0; t < 4; t++)
            af[t] = *(const bf16x8*)(As + (wm + t * 16 + l16) * 32 + quad * 8);
#pragma unroll
        for (int t = 0; t < 4; t++)
            bfr[t] = *(const bf16x8*)(Bs + (wn + t * 16 + l16) * 32 + quad * 8);
#pragma unroll
        for (int i = 0; i < 4; i++)
#pragma unroll
            for (int j = 0; j < 4; j++)
                acc[i][j] = __builtin_amdgcn_mfma_f32_16x16x32_bf16(
                    af[i], bfr[j], acc[i][j], 0, 0, 0);
    }

#pragma unroll
    for (int j = 0; j < 4; j++) {
        int col  = n0 + wn + j * 16 + l16;
        int colc = col < N ? col : N - 1;
        float bv = bias ? bias[colc] : 0.f;
#pragma unroll
        for (int i = 0; i < 4; i++) {
#pragma unroll
            for (int r = 0; r < 4; r++) {
                int row = m0 + wm + i * 16 + quad * 4 + r;
                float v = acc[i][j][r] * scale + bv;
                if (flags & 1)
                    v = 0.5f * v * (1.f + erff(v * 0.70710678118654752f));
                if (row < M && col < N) {
                    if (Cfb) Cfb[(long)row * ldc + col] = v;
                    else     Cb [(long)row * ldc + col] = f2bf(v);
                }
            }
        }
    }
}

// ---------------------------------------------------------------------------
// Flash attention: O = softmax(scale*Q K^T + mask) V, head dim 64, L = 512.
//   Q,K,O: (b, 512, 1024) bf16, head h at cols h*64..h*64+63
//   VT   : (bh, 64, 512) bf16 (per-head V^T)
// grid (bh=cb*16, qt=8): bh FAST so the 8 qt-blocks of one head land on the
// SAME XCD (256 % 8 == 0) -> K/VT fetched once per XCD, L2-served after.
// Block: 4 waves, 64 q-rows. K-tile(128x64) + VT-tile(64x128) staged in LDS,
// shared by all waves; P does C-layout -> A-layout via per-wave LDS (m120).
// ---------------------------------------------------------------------------
__global__ __launch_bounds__(256) void flash_kernel(
    const u16* __restrict__ Q, const u16* __restrict__ K,
    const u16* __restrict__ VT, u16* __restrict__ O,
    const float* __restrict__ mask, int causal)
{
    __shared__ __align__(16) u16 Ks[128 * 72];    // keys x dims, pad 64->72
    __shared__ __align__(16) u16 Vs[64 * 136];    // dims x keys, pad 128->136
    __shared__ __align__(16) u16 Ps[64 * 136];    // q-rows x keys (per-wave rows)
    const int tid  = threadIdx.x;
    const int wave = tid >> 6, lane = tid & 63;
    const int quad = lane >> 4, l16 = lane & 15;
    const int bh = blockIdx.x, qt = blockIdx.y, b = bh >> 4, h = bh & 15;
    const int qbase = qt * 64 + wave * 16;

    // Q A-frags (m=l16, k=quad*8+j) held for the whole kernel
    const u16* qp = Q + ((long)b * LTOK + qbase + l16) * DDIM + h * 64 + quad * 8;
    bf16x8 aq0 = *(const bf16x8*)(qp);
    bf16x8 aq1 = *(const bf16x8*)(qp + 32);

    f32x4 oacc[4];
#pragma unroll
    for (int jd = 0; jd < 4; jd++) oacc[jd] = (f32x4){0.f, 0.f, 0.f, 0.f};
    f32x4 m_st = (f32x4){-3.0e38f, -3.0e38f, -3.0e38f, -3.0e38f};
    f32x4 l_st = (f32x4){0.f, 0.f, 0.f, 0.f};

    u16* Pw = Ps + (wave * 16) * 136;   // per-wave private rows

    // staging maps
    const int krow = tid >> 3,       kcol = (tid & 7) << 3;   // K: 32 rows/issue
    const int vrow = tid >> 2,       vcol = (tid & 3) << 3;   // VT: 64 rows, 4x8 cols/issue
    const u16* gK = K + ((long)b * LTOK + krow) * DDIM + h * 64 + kcol;
    const u16* gV = VT + ((long)bh * 64 + vrow) * LTOK + vcol;

    const int nkt = causal ? ((qt * 64 + 63) >> 7) + 1 : (LTOK >> 7);
    for (int kt = 0; kt < nkt; kt++) {
        const int k0 = kt << 7;

        __syncthreads();   // prior iteration's Ks/Vs reads complete
#pragma unroll
        for (int i = 0; i < 4; i++)     // K-tile: 128 rows x 64 dims
            *(u16x8*)(Ks + (i * 32 + krow) * 72 + kcol) =
                *(const u16x8*)(gK + (long)(k0 + i * 32) * DDIM);
#pragma unroll
        for (int i = 0; i < 4; i++)     // VT-tile: 64 rows x 128 keys
            *(u16x8*)(Vs + vrow * 136 + i * 32 + vcol) =
                *(const u16x8*)(gV + k0 + i * 32);
        __syncthreads();

        // S-tile = Q K^T : C-layout (row q = quad*4+r, col key = j*16+l16)
        f32x4 s[8];
#pragma unroll
        for (int j = 0; j < 8; j++) {
            bf16x8 bk0 = *(const bf16x8*)(Ks + (j * 16 + l16) * 72 + quad * 8);
            bf16x8 bk1 = *(const bf16x8*)(Ks + (j * 16 + l16) * 72 + 32 + quad * 8);
            f32x4 z = (f32x4){0.f, 0.f, 0.f, 0.f};
            z = __builtin_amdgcn_mfma_f32_16x16x32_bf16(aq0, bk0, z, 0, 0, 0);
            s[j] = __builtin_amdgcn_mfma_f32_16x16x32_bf16(aq1, bk1, z, 0, 0, 0);
        }

        // scale + mask, per-row tile max
        f32x4 tmax = (f32x4){-3.0e38f, -3.0e38f, -3.0e38f, -3.0e38f};
#pragma unroll
        for (int j = 0; j < 8; j++) {
            const int col = k0 + j * 16 + l16;
            float mval = causal ? mask[b * LTOK + col] : 0.f;
#pragma unroll
            for (int r = 0; r < 4; r++) {
                float v = s[j][r] * 0.125f;
                if (causal) {
                    const int row = qbase + quad * 4 + r;
                    float mk = (col <= row) ? mval : 0.f;
                    v += (1.f - mk) * (-10000.f);
                }
                s[j][r] = v;
                tmax[r] = fmaxf(tmax[r], v);
            }
        }
#pragma unroll
        for (int ofs = 1; ofs <= 8; ofs <<= 1) {
#pragma unroll
            for (int r = 0; r < 4; r++)
                tmax[r] = fmaxf(tmax[r], __shfl_xor(tmax[r], ofs));
        }

        f32x4 mnew, alpha, rsum;
#pragma unroll
        for (int r = 0; r < 4; r++) {
            mnew[r]  = fmaxf(m_st[r], tmax[r]);
            alpha[r] = __expf(m_st[r] - mnew[r]);
            rsum[r]  = 0.f;
        }
#pragma unroll
        for (int j = 0; j < 8; j++) {
#pragma unroll
            for (int r = 0; r < 4; r++) {
                float p = __expf(s[j][r] - mnew[r]);
                rsum[r] += p;
                Pw[(quad * 4 + r) * 136 + j * 16 + l16] = f2bf(p);
            }
        }
#pragma unroll
        for (int ofs = 1; ofs <= 8; ofs <<= 1) {
#pragma unroll
            for (int r = 0; r < 4; r++)
                rsum[r] += __shfl_xor(rsum[r], ofs);
        }
#pragma unroll
        for (int r = 0; r < 4; r++) {
            l_st[r] = l_st[r] * alpha[r] + rsum[r];
            m_st[r] = mnew[r];
        }
#pragma unroll
        for (int jd = 0; jd < 4; jd++)
#pragma unroll
            for (int r = 0; r < 4; r++) oacc[jd][r] *= alpha[r];

        // O += P @ V : A = P (A-layout from LDS), B = VT rows (LDS)
#pragma unroll
        for (int kk = 0; kk < 4; kk++) {
            bf16x8 ap = *(const bf16x8*)(Ps + (wave * 16 + l16) * 136
                                            + kk * 32 + quad * 8);
#pragma unroll
            for (int jd = 0; jd < 4; jd++) {
                bf16x8 bv = *(const bf16x8*)(Vs + (jd * 16 + l16) * 136
                                                + kk * 32 + quad * 8);
                oacc[jd] = __builtin_amdgcn_mfma_f32_16x16x32_bf16(ap, bv, oacc[jd], 0, 0, 0);
            }
        }
    }

    // O write: element (q = quad*4+r, d = jd*16+l16)
#pragma unroll
    for (int jd = 0; jd < 4; jd++) {
#pragma unroll
        for (int r = 0; r < 4; r++) {
            long row = (long)b * LTOK + qbase + quad * 4 + r;
            O[row * DDIM + h * 64 + jd * 16 + l16] = f2bf(oacc[jd][r] / l_st[r]);
        }
    }
}

// out = LayerNorm(a + b) * g + beta.  a: bf16.  b: bf16 unless b32 (fp32).
// Output: bf16 (o) unless of != nullptr (fp32).  Row length 1024.
__global__ __launch_bounds__(256) void add_ln_kernel(
    const u16* __restrict__ a, const u16* __restrict__ b,
    const float* __restrict__ b32,
    const float* __restrict__ g, const float* __restrict__ bt,
    u16* __restrict__ o, float* __restrict__ of)
{
    long row = blockIdx.x;
    int tid = threadIdx.x;
    __shared__ float red[4];
    const u16* ar = a + row * DDIM;
    float xv[4]; float s = 0.f;
#pragma unroll
    for (int i = 0; i < 4; i++) {
        int c = tid + 256 * i;
        float sum = bf2f(ar[c]) + (b32 ? b32[row * DDIM + c] : bf2f(b[row * DDIM + c]));
        xv[i] = fminf(fmaxf(sum, -1.0e18f), 1.0e18f);
        s += xv[i];
    }
#pragma unroll
    for (int ofs = 32; ofs >= 1; ofs >>= 1) s += __shfl_xor(s, ofs);
    int wave = tid >> 6, lane = tid & 63;
    if (lane == 0) red[wave] = s;
    __syncthreads();
    float mu = (red[0] + red[1] + red[2] + red[3]) * (1.f / 1024.f);
    __syncthreads();
    float v = 0.f;
#pragma unroll
    for (int i = 0; i < 4; i++) { float d = xv[i] - mu; v += d * d; }
#pragma unroll
    for (int ofs = 32; ofs >= 1; ofs >>= 1) v += __shfl_xor(v, ofs);
    if (lane == 0) red[wave] = v;
    __syncthreads();
    float var = (red[0] + red[1] + red[2] + red[3]) * (1.f / 1024.f);
    float inv = rsqrtf(var + 1e-6f);
#pragma unroll
    for (int i = 0; i < 4; i++) {
        int c = tid + 256 * i;
        float r = (xv[i] - mu) * inv * g[c] + bt[c];
        if (of) of[row * DDIM + c] = r;
        else    o [row * DDIM + c] = f2bf(r);
    }
}

// fp32 -> bf16 conversion, 8 elements/thread.
__global__ __launch_bounds__(256) void cvt_kernel(
    const float* __restrict__ src, u16* __restrict__ dst)
{
    long i = ((long)blockIdx.x * 256 + threadIdx.x) * 8;
    u16x8 o;
#pragma unroll
    for (int j = 0; j < 8; j++) o[j] = f2bf(src[i + j]);
    *(u16x8*)(dst + i) = o;
}

// Transpose+cvt the 8 fp32 weight matrices (1024x1024): WT[n][k] = bf16(W[k][n])
__global__ __launch_bounds__(256) void wt_kernel(
    const float* w0, const float* w1, const float* w2, const float* w3,
    const float* w4, const float* w5, const float* w6, const float* w7,
    u16* __restrict__ wt)
{
    const float* srcs[8] = {w0, w1, w2, w3, w4, w5, w6, w7};
    const float* w = srcs[blockIdx.z];
    u16* o = wt + (long)blockIdx.z * DDIM * DDIM;
    __shared__ u16 t[32][33];
    int tx = threadIdx.x & 31, ty = threadIdx.x >> 5;
    int c0 = blockIdx.x << 5, r0 = blockIdx.y << 5;
#pragma unroll
    for (int i = 0; i < 4; i++)
        t[ty + 8 * i][tx] = f2bf(w[(long)(r0 + ty + 8 * i) * DDIM + c0 + tx]);
    __syncthreads();
#pragma unroll
    for (int i = 0; i < 4; i++)
        o[(long)(c0 + ty + 8 * i) * DDIM + r0 + tx] = t[tx][ty + 8 * i];
}

// vt[(b*NH+h)*64 + dd][k] = v[b*LTOK + k][h*64 + dd]   (per-head V transpose)
__global__ __launch_bounds__(256) void vtrans_kernel(
    const u16* __restrict__ v, u16* __restrict__ vt)
{
    int bh = blockIdx.y; int b = bh >> 4, h = bh & 15;
    int k0 = blockIdx.x << 5;
    __shared__ __align__(16) u16 t[32 * 72];
    int kk = threadIdx.x >> 3, c = (threadIdx.x & 7) << 3;
    u16x8 val = *(const u16x8*)(v + ((long)b * LTOK + k0 + kk) * DDIM + h * 64 + c);
    *(u16x8*)(t + kk * 72 + c) = val;
    __syncthreads();
    int dd = threadIdx.x >> 2, k2 = (threadIdx.x & 3) << 3;
    u16x8 o;
#pragma unroll
    for (int j = 0; j < 8; j++) o[j] = t[(k2 + j) * 72 + dd];
    *(u16x8*)(vt + ((long)bh * 64 + dd) * LTOK + k0 + k2) = o;
}

extern "C" void kernel_launch(void* const* d_in, const int* in_sizes, int n_in,
                              void* d_out, int out_size, void* d_ws, size_t ws_size,
                              hipStream_t stream)
{
    const float* x     = (const float*)d_in[0];
    const float* dmsk  = (const float*)d_in[1];
    const float* enc   = (const float*)d_in[2];
    const float* sa_wq = (const float*)d_in[3];  const float* sa_bq = (const float*)d_in[4];
    const float* sa_wk = (const float*)d_in[5];  const float* sa_bk = (const float*)d_in[6];
    const float* sa_wv = (const float*)d_in[7];  const float* sa_bv = (const float*)d_in[8];
    const float* n1_g  = (const float*)d_in[9];  const float* n1_b  = (const float*)d_in[10];
    const float* ca_wq = (const float*)d_in[11]; const float* ca_bq = (const float*)d_in[12];
    const float* ca_wk = (const float*)d_in[13]; const float* ca_bk = (const float*)d_in[14];
    const float* ca_wv = (const float*)d_in[15]; const float* ca_bv = (const float*)d_in[16];
    const float* n2_g  = (const float*)d_in[17]; const float* n2_b  = (const float*)d_in[18];
    const float* int_w = (const float*)d_in[19]; const float* int_b = (const float*)d_in[20];
    const float* out_w = (const float*)d_in[21]; const float* out_b = (const float*)d_in[22];
    const float* out_g = (const float*)d_in[23]; const float* out_bt= (const float*)d_in[24];

    float* outp = (float*)d_out;
    float* visp = outp + (long)NBATCH * LTOK * DDIM;   // attention_vis (fp32)

    // --- workspace: chunk over batches; 7 act buffers / batch + WT ---
    const size_t WTB  = (size_t)8 * DDIM * DDIM * 2;            // 16 MiB
    const size_t BUF1 = (size_t)LTOK * DDIM * 2;                // 1 MiB / batch
    int cb = 16;
    while (cb > 1 && WTB + (size_t)cb * 7 * BUF1 + 8192 > ws_size)
        cb >>= 1;

    char* ws = (char*)d_ws;
    size_t off = 0;
    auto alloc = [&](size_t bytes) -> u16* {
        u16* p = (u16*)(ws + off);
        off += (bytes + 255) & ~(size_t)255;
        return p;
    };
    u16* Bq  = alloc((size_t)cb * BUF1);
    u16* Bk  = alloc((size_t)cb * BUF1);
    u16* Bv  = alloc((size_t)cb * BUF1);
    u16* Bt  = alloc((size_t)cb * BUF1);
    u16* Bt2 = alloc((size_t)cb * BUF1);
    u16* Xb  = alloc((size_t)cb * BUF1);
    u16* Eb  = alloc((size_t)cb * BUF1);
    u16* WT  = alloc(WTB);
    // no memset needed: every region fully written before read.

    u16* Wsaq = WT + 0L * DDIM * DDIM; u16* Wsak = WT + 1L * DDIM * DDIM;
    u16* Wsav = WT + 2L * DDIM * DDIM; u16* Wcaq = WT + 3L * DDIM * DDIM;
    u16* Wcak = WT + 4L * DDIM * DDIM; u16* Wcav = WT + 5L * DDIM * DDIM;
    u16* Wint = WT + 6L * DDIM * DDIM; u16* Wout = WT + 7L * DDIM * DDIM;

    auto gemm = [&](const u16* A, int lda, long sA1, long sA2,
                    const u16* B, int ldb, long sB1, long sB2,
                    u16* C, float* Cf, int ldc, long sC1, long sC2,
                    int M, int N, int K, int Z, int zdiv,
                    const float* bias, float scale, int flags) {
        int tM = (M + 127) / 128, tN = (N + 127) / 128;
        gemm_bt_kernel<<<dim3(tM * tN, Z), dim3(256), 0, stream>>>(
            A, lda, sA1, sA2, B, ldb, sB1, sB2, C, Cf, ldc, sC1, sC2,
            M, N, K, zdiv, bias, scale, flags);
    };

    const long SLD = (long)LTOK * DDIM;       // per-batch row-block stride
    const long SSC = (long)LTOK * LTOK;       // vis elems per batch

    // 0) weight transposes + bf16 cvt (once per call)
    wt_kernel<<<dim3(32, 32, 8), dim3(256), 0, stream>>>(
        sa_wq, sa_wk, sa_wv, ca_wq, ca_wk, ca_wv, int_w, out_w, WT);

    for (int b0 = 0; b0 < NBATCH; b0 += cb) {
        const float* xc = x   + (long)b0 * SLD;
        const float* ec = enc + (long)b0 * SLD;
        const int M = cb * LTOK;
        const int Z = cb * NH;
        const int cvtg = (int)(((long)M * DDIM) / (256 * 8));

        // a) fp32 -> bf16 activation copies
        cvt_kernel<<<dim3(cvtg), dim3(256), 0, stream>>>(xc, Xb);
        cvt_kernel<<<dim3(cvtg), dim3(256), 0, stream>>>(ec, Eb);

        // 1) self-attn q,k,v projections
        gemm(Xb, DDIM, 0, 0, Wsaq, DDIM, 0, 0, Bq, nullptr, DDIM, 0, 0, M, DDIM, DDIM, 1, 1, sa_bq, 1.f, 0);
        gemm(Xb, DDIM, 0, 0, Wsak, DDIM, 0, 0, Bk, nullptr, DDIM, 0, 0, M, DDIM, DDIM, 1, 1, sa_bk, 1.f, 0);
        gemm(Xb, DDIM, 0, 0, Wsav, DDIM, 0, 0, Bv, nullptr, DDIM, 0, 0, M, DDIM, DDIM, 1, 1, sa_bv, 1.f, 0);
        vtrans_kernel<<<dim3(16, Z), dim3(256), 0, stream>>>(Bv, Bt);

        // 2) self-attention (flash, causal+padding), ctx -> Bv
        flash_kernel<<<dim3(Z, 8), dim3(256), 0, stream>>>(
            Bq, Bk, Bt, Bv, dmsk + (long)b0 * LTOK, 1);

        // 3) h = LN(ctx + x_fp32) -> Bq
        add_ln_kernel<<<dim3(M), dim3(256), 0, stream>>>(
            Bv, nullptr, xc, n1_g, n1_b, Bq, nullptr);

        // 4) cross projections: cq->Bk, ck->Bv, cv->Bt
        gemm(Bq, DDIM, 0, 0, Wcaq, DDIM, 0, 0, Bk, nullptr, DDIM, 0, 0, M, DDIM, DDIM, 1, 1, ca_bq, 1.f, 0);
        gemm(Eb, DDIM, 0, 0, Wcak, DDIM, 0, 0, Bv, nullptr, DDIM, 0, 0, M, DDIM, DDIM, 1, 1, ca_bk, 1.f, 0);
        gemm(Eb, DDIM, 0, 0, Wcav, DDIM, 0, 0, Bt, nullptr, DDIM, 0, 0, M, DDIM, DDIM, 1, 1, ca_bv, 1.f, 0);

        // 5) attention_vis = (cq @ ck^T) / 128  -> fp32 d_out
        gemm(Bk, DDIM, SLD, 0, Bv, DDIM, SLD, 0,
             nullptr, visp + (long)b0 * SSC, LTOK, SSC, 0,
             LTOK, LTOK, DDIM, cb, 1, nullptr, 1.f / 128.f, 0);

        // 6) cross-attention (flash, no mask): vt(cv)->Bt2; ctx -> Bt
        vtrans_kernel<<<dim3(16, Z), dim3(256), 0, stream>>>(Bt, Bt2);
        flash_kernel<<<dim3(Z, 8), dim3(256), 0, stream>>>(
            Bk, Bv, Bt2, Bt, nullptr, 0);

        // 7) h2 = LN(h + cactx) -> Bv
        add_ln_kernel<<<dim3(M), dim3(256), 0, stream>>>(
            Bq, Bt, nullptr, n2_g, n2_b, Bv, nullptr);

        // 8) inter = gelu(h2 @ int_w + int_b) -> Bk
        gemm(Bv, DDIM, 0, 0, Wint, DDIM, 0, 0, Bk, nullptr, DDIM, 0, 0, M, DDIM, DDIM, 1, 1, int_b, 1.f, 1);
        // 9) G = inter @ out_w + out_b -> Bt
        gemm(Bk, DDIM, 0, 0, Wout, DDIM, 0, 0, Bt, nullptr, DDIM, 0, 0, M, DDIM, DDIM, 1, 1, out_b, 1.f, 0);
        // 10) out = LN(G + inter) -> fp32 d_out
        add_ln_kernel<<<dim3(M), dim3(256), 0, stream>>>(
            Bt, Bk, nullptr, out_g, out_bt, nullptr, outp + (long)b0 * SLD);
    }
}